// Round 12
// baseline (478.130 us; speedup 1.0000x reference)
//
#include <hip/hip_runtime.h>
#include <cstdint>
#include <cstddef>

#define NN 50000
#define NE 800000
#define DD 128

#define NBK 391      // buckets of 128 nodes: (NN+127)>>7
#define BSLOT 4096   // slack slots per bucket (avg 2046, sd ~45 -> 45 sigma headroom)

static_assert(NN % 16 == 0, "node tiles");
static_assert(NE % 16 == 0, "edge tiles");
static_assert(((NN + 127) >> 7) == NBK, "bucket count");

typedef _Float16 h16_t;
typedef h16_t h16x8 __attribute__((ext_vector_type(8)));
typedef h16_t h16x4 __attribute__((ext_vector_type(4)));
typedef float f32x4 __attribute__((ext_vector_type(4)));
typedef float f32x16 __attribute__((ext_vector_type(16)));

// fast gelu: x * sigmoid(2*0.79788456*(x+0.044715x^3)) via v_exp_f32 + rcp (~1e-3 abs err)
__device__ __forceinline__ float gelu_f(float x) {
    float u = x * x;
    float t = fmaf(u, -0.1029442445f, -2.3021184019f);  // -(2log2e)*0.79788456*(1+0.044715u)
    float s = __builtin_amdgcn_exp2f(x * t);
    return x * __builtin_amdgcn_rcpf(1.0f + s);
}

// fragment-major weight index for 16x16x32 MFMA: element (ch,k) -> ((t*4+kb)*4+q)*16+n)*8+j
__device__ __forceinline__ int frag_idx(int ch, int k) {
    int t = ch >> 4, n = ch & 15;
    int kb = k >> 5, r = k & 31, q = r >> 3, j = r & 7;
    return ((((t * 4 + kb) * 4 + q) * 16 + n) << 3) + j;
}

// fragment-major weight index for 32x32x16 MFMA: lane(m=l&31,q=l>>5) holds W[t*32+m][kc*16+q*8+j]
__device__ __forceinline__ int frag32_idx(int ch, int k) {
    int t = ch >> 5, m = ch & 31;
    int kc = k >> 4, q = (k >> 3) & 1, j = k & 7;
    return ((((t * 8 + kc) * 2 + q) * 32 + m) << 3) + j;
}

// ---------------- feat f32 -> fp16 ----------------
__global__ __launch_bounds__(256) void convert_feat_kernel(
    const float* __restrict__ feat, h16_t* __restrict__ fb)
{
    int i = blockIdx.x * 256 + threadIdx.x;  // quad index; NN*DD/4 = 1.6M exact
    f32x4 v = ((const f32x4*)feat)[i];
    h16x4 o;
    o[0] = (h16_t)v[0]; o[1] = (h16_t)v[1]; o[2] = (h16_t)v[2]; o[3] = (h16_t)v[3];
    ((h16x4*)fb)[i] = o;
}

// ---------------- prep: combine + convert weights, combine biases ----------------
// W_Sf = asrc+asub, W_Df = adst-asub (16x16 frag-major, node kernel -> us/ud).
// W_amulf: 32x32 frag-major (edge kernel). All fp16.
__global__ __launch_bounds__(256) void prep_kernel(
    const float* __restrict__ W_asrc, const float* __restrict__ b_asrc,
    const float* __restrict__ W_adst, const float* __restrict__ b_adst,
    const float* __restrict__ W_asub, const float* __restrict__ b_asub,
    const float* __restrict__ W_amul, const float* __restrict__ b_amul,
    const float* __restrict__ W_pool, const float* __restrict__ W_pool2,
    const float* __restrict__ W_self, const float* __restrict__ b_self,
    const float* __restrict__ W_neigh, const float* __restrict__ b_neigh,
    const float* __restrict__ W_neigh2, const float* __restrict__ b_neigh2,
    const float* __restrict__ W_mlp,
    h16_t* __restrict__ W_Sf, h16_t* __restrict__ W_Df, h16_t* __restrict__ W_amulf,
    h16_t* __restrict__ W_poolf, h16_t* __restrict__ W_pool2f,
    h16_t* __restrict__ W_selff, h16_t* __restrict__ W_neighf, h16_t* __restrict__ W_neigh2f,
    h16_t* __restrict__ W_mlpf,
    float* __restrict__ b_e, float* __restrict__ b_rst)
{
    int gid = blockIdx.x * 256 + threadIdx.x;  // 64 blocks * 256 = 16384 = DD*DD
    float sub = W_asub[gid];
    int ch = gid >> 7, k = gid & 127;
    int fi = frag_idx(ch, k);
    W_Sf[fi] = (h16_t)(W_asrc[gid] + sub);
    W_Df[fi] = (h16_t)(W_adst[gid] - sub);
    W_amulf[frag32_idx(ch, k)] = (h16_t)W_amul[gid];
    W_poolf[fi]   = (h16_t)W_pool[gid];
    W_pool2f[fi]  = (h16_t)W_pool2[gid];
    W_selff[fi]   = (h16_t)W_self[gid];
    W_neighf[fi]  = (h16_t)W_neigh[gid];
    W_neigh2f[fi] = (h16_t)W_neigh2[gid];
    W_mlpf[fi]            = (h16_t)W_mlp[gid];
    W_mlpf[DD * DD + fi]  = (h16_t)W_mlp[DD * DD + gid];
    if (gid < DD) {
        b_e[gid]   = b_asub[gid] + b_amul[gid] + b_asrc[gid] + b_adst[gid];
        b_rst[gid] = b_self[gid] + b_neigh[gid] + b_neigh2[gid];
    }
}

// ---------------- bucket sort pass 1: LDS-privatized histogram + chunked scatter ----------------
__global__ __launch_bounds__(256) void scatter_bucket_kernel(
    const int* __restrict__ src, const int* __restrict__ dst,
    int* __restrict__ gcursor, int2* __restrict__ ebuf)
{
    __shared__ int cnt[NBK];
    __shared__ int ofs[NBK];
    int t = threadIdx.x;
    for (int b = t; b < NBK; b += 256) cnt[b] = 0;
    __syncthreads();
    int qbase = blockIdx.x * 1024 + t;
    int4 s4[4], d4[4];
    bool valid[4];
#pragma unroll
    for (int k = 0; k < 4; k++) {
        int q = qbase + k * 256;
        valid[k] = q < NE / 4;
        if (valid[k]) {
            s4[k] = ((const int4*)src)[q];
            d4[k] = ((const int4*)dst)[q];
#pragma unroll
            for (int j = 0; j < 4; j++)
                atomicAdd(&cnt[((&d4[k].x)[j]) >> 7], 1);
        }
    }
    __syncthreads();
    for (int b = t; b < NBK; b += 256) {
        int c = cnt[b];
        ofs[b] = c ? atomicAdd(&gcursor[b], c) : 0;
    }
    __syncthreads();
#pragma unroll
    for (int k = 0; k < 4; k++) {
        if (valid[k]) {
#pragma unroll
            for (int j = 0; j < 4; j++) {
                int d = (&d4[k].x)[j];
                int b = d >> 7;
                int p = atomicAdd(&ofs[b], 1);
                int2 pk;
                pk.x = (&s4[k].x)[j];
                pk.y = d;
                ebuf[(size_t)b * BSLOT + p] = pk;
            }
        }
    }
}

// ---------------- bucket sort pass 2: exact CSR within each bucket (fused prefix) ----------------
// dbase = sum(gcursor[0..B)) computed per-block via LDS reduce (391 ints, trivial) —
// replaces the standalone bucket_scan kernel.
__global__ __launch_bounds__(256) void finalize_csr_kernel(
    const int2* __restrict__ ebuf, const int* __restrict__ gcursor,
    int2* __restrict__ csr, int* __restrict__ offsets, int* __restrict__ deg)
{
    __shared__ int lcnt[128];
    __shared__ int nbase[128];
    __shared__ int pre[128];
    __shared__ int redbuf[256];
    int B = blockIdx.x, t = threadIdx.x;
    int v0 = B << 7;
    int cnt = gcursor[B];
    // block-local exclusive prefix over bucket counts
    int partial = 0;
    for (int i = t; i < B; i += 256) partial += gcursor[i];
    redbuf[t] = partial;
    __syncthreads();
#pragma unroll
    for (int d = 128; d > 0; d >>= 1) {
        if (t < d) redbuf[t] += redbuf[t + d];
        __syncthreads();
    }
    int dbase = redbuf[0];
    const int2* eb = ebuf + (size_t)B * BSLOT;
    if (t < 128) lcnt[t] = 0;
    __syncthreads();
    for (int i = t; i < cnt; i += 256)
        atomicAdd(&lcnt[eb[i].y - v0], 1);
    __syncthreads();
    int c = (t < 128) ? lcnt[t] : 0;
    if (t < 128) pre[t] = c;
    __syncthreads();
#pragma unroll
    for (int d = 1; d < 128; d <<= 1) {
        int x = (t >= d && t < 128) ? pre[t - d] : 0;
        __syncthreads();
        if (t < 128) pre[t] += x;
        __syncthreads();
    }
    if (t < 128) {
        int nb = dbase + pre[t] - c;  // exclusive prefix -> node base in dense csr
        nbase[t] = nb;
        int v = v0 + t;
        if (v < NN) { offsets[v] = nb; deg[v] = c; }
        lcnt[t] = 0;
    }
    __syncthreads();
    for (int i = t; i < cnt; i += 256) {
        int2 pk = eb[i];
        int j = pk.y - v0;
        int pos = nbase[j] + atomicAdd(&lcnt[j], 1);
        csr[pos] = pk;
    }
}

// ---------------- node_linear: MFMA -> LDS transpose -> wide coalesced stores ----------------
template <bool GELU>
__device__ __forceinline__ void mm16_to_lds(
    const h16x8 a[4], const h16_t* __restrict__ Wf, const float* __restrict__ bias,
    h16_t* __restrict__ L, int n, int q, int lane)
{
#pragma unroll
    for (int t = 0; t < 8; t++) {
        f32x4 acc = {0.f, 0.f, 0.f, 0.f};
#pragma unroll
        for (int kb = 0; kb < 4; kb++) {
            h16x8 b = *(const h16x8*)(Wf + (((t * 4 + kb) * 64 + lane) << 3));
            acc = __builtin_amdgcn_mfma_f32_16x16x32_f16(a[kb], b, acc, 0, 0, 0);
        }
        int ch = t * 16 + n;
        float bv = bias ? bias[ch] : 0.0f;
#pragma unroll
        for (int r = 0; r < 4; r++) {
            float v = acc[r] + bv;
            L[(q * 4 + r) * 136 + ch] = (h16_t)(GELU ? gelu_f(v) : v);
        }
    }
}

__global__ __launch_bounds__(256) void node_linear_kernel(
    const h16_t* __restrict__ fb,
    const h16_t* __restrict__ W_poolf, const float* __restrict__ b_pool,
    const h16_t* __restrict__ W_pool2f, const float* __restrict__ b_pool2,
    const h16_t* __restrict__ W_Sf, const float* __restrict__ b_e,
    const h16_t* __restrict__ W_Df,
    h16_t* __restrict__ hh, h16_t* __restrict__ us, h16_t* __restrict__ ud)
{
    __shared__ __align__(16) h16_t Lh[4][16 * 136];
    __shared__ __align__(16) h16_t Lh2[4][16 * 136];
    int wave = threadIdx.x >> 6;
    int wid = blockIdx.x * 4 + wave;
    if (wid >= NN / 16) return;
    int lane = threadIdx.x & 63, n = lane & 15, q = lane >> 4;
    int nb = wid * 16;
    h16_t* lh = Lh[wave];
    h16_t* lh2 = Lh2[wave];
    h16x8 a[4];
#pragma unroll
    for (int kb = 0; kb < 4; kb++)
        a[kb] = *(const h16x8*)(fb + (size_t)(nb + n) * DD + kb * 32 + q * 8);

    // h -> lh, h2 -> lh2 (gelu'd fp16)
    mm16_to_lds<true>(a, W_poolf, b_pool, lh, n, q, lane);
    mm16_to_lds<true>(a, W_pool2f, b_pool2, lh2, n, q, lane);
    __builtin_amdgcn_wave_barrier();
    // interleaved hh store: chunk c (16B) = {h[4c],h[4c+1],h2[4c],h2[4c+1],h[4c+2],h[4c+3],h2[4c+2],h2[4c+3]}
#pragma unroll
    for (int i = 0; i < 8; i++) {
        int r = 2 * i + (lane >> 5);
        int c = lane & 31;
        h16x4 xh = *(const h16x4*)(lh + r * 136 + 4 * c);
        h16x4 x2 = *(const h16x4*)(lh2 + r * 136 + 4 * c);
        h16x8 o;
        o[0] = xh[0]; o[1] = xh[1]; o[2] = x2[0]; o[3] = x2[1];
        o[4] = xh[2]; o[5] = xh[3]; o[6] = x2[2]; o[7] = x2[3];
        *(h16x8*)(hh + (size_t)(nb + r) * 256 + 8 * c) = o;
    }
    __builtin_amdgcn_wave_barrier();
    // us = (W_asrc+W_asub)·f + b_e
    mm16_to_lds<false>(a, W_Sf, b_e, lh, n, q, lane);
    __builtin_amdgcn_wave_barrier();
#pragma unroll
    for (int i = 0; i < 4; i++) {
        int r = 4 * i + (lane >> 4);
        int c = lane & 15;
        *(h16x8*)(us + (size_t)(nb + r) * 128 + 8 * c) = *(const h16x8*)(lh + r * 136 + 8 * c);
    }
    __builtin_amdgcn_wave_barrier();
    // ud = (W_adst-W_asub)·f
    mm16_to_lds<false>(a, W_Df, nullptr, lh, n, q, lane);
    __builtin_amdgcn_wave_barrier();
#pragma unroll
    for (int i = 0; i < 4; i++) {
        int r = 4 * i + (lane >> 4);
        int c = lane & 15;
        *(h16x8*)(ud + (size_t)(nb + r) * 128 + 8 * c) = *(const h16x8*)(lh + r * 136 + 8 * c);
    }
}

// ---------------- per-edge score over dst-sorted list (v6: 512-thread / 64-edge tiles) ----------------
// e_ch = gelu( W_amul·(fs∘fd) + us[src] + ud[dst] ). Edges in CSR(dst) order.
// 8 waves: wave w -> ch-tile t = w&3, edge-group g = w>>2 (32 edges each). Barriers,
// partials and the scatter tail amortize over 64 edges; 4 blocks x 8 waves = 32 waves/CU.
#define ES_NBLK 1250
#define ES_ITERS (NE / 64 / ES_NBLK)   // 10

__global__ __launch_bounds__(512, 8) void edge_score_kernel(
    const h16_t* __restrict__ fb,
    const h16_t* __restrict__ us, const h16_t* __restrict__ ud,
    const h16_t* __restrict__ W_amulf,
    const float* __restrict__ w_aout, const float* __restrict__ b_aout,
    int2* __restrict__ csr)
{
    __shared__ __align__(16) h16_t sP[64 * 128];
    __shared__ __align__(16) h16_t sU[64 * 128];
    __shared__ float partials[64 * 5];   // [edge][chtile], stride 5 to kill bank conflicts
    __shared__ float sWa[128];
    int tid = threadIdx.x;
    int wave = tid >> 6, lane = tid & 63;
    int n = lane & 31, q = lane >> 5;
    int t = wave & 3;   // channel tile (32 ch)
    int g = wave >> 2;  // edge group (32 edges)

    if (tid < 128) sWa[tid] = w_aout[tid];

    // persistent weight A-frags: lane(m=n,q) holds W[t*32+n][kc*16+q*8 .. +7]
    h16x8 wAm[8];
#pragma unroll
    for (int kc = 0; kc < 8; kc++)
        wAm[kc] = *(const h16x8*)(W_amulf + ((((t * 8 + kc) * 2 + q) * 32 + n) << 3));
    float bout = b_aout[0];

    // staging role: thread -> edges sed, sed+32; 16B chunk sc (0..15)
    int sed = tid >> 4, sc = tid & 15;

    // prefetch tile 0 ({src,dst} read sequentially from csr)
    int e0 = blockIdx.x * 64;
    int2 pk0 = csr[e0 + sed];
    int2 pk1 = csr[e0 + sed + 32];
    h16x8 pfs0 = *(const h16x8*)(fb + (size_t)pk0.x * DD + sc * 8);
    h16x8 pfd0 = *(const h16x8*)(fb + (size_t)pk0.y * DD + sc * 8);
    h16x8 pus0 = *(const h16x8*)(us + (size_t)pk0.x * DD + sc * 8);
    h16x8 pud0 = *(const h16x8*)(ud + (size_t)pk0.y * DD + sc * 8);
    h16x8 pfs1 = *(const h16x8*)(fb + (size_t)pk1.x * DD + sc * 8);
    h16x8 pfd1 = *(const h16x8*)(fb + (size_t)pk1.y * DD + sc * 8);
    h16x8 pus1 = *(const h16x8*)(us + (size_t)pk1.x * DD + sc * 8);
    h16x8 pud1 = *(const h16x8*)(ud + (size_t)pk1.y * DD + sc * 8);

    for (int it = 0; it < ES_ITERS; it++) {
        int eb = (blockIdx.x + it * ES_NBLK) * 64;
        {
            h16x8 pp = pfs0 * pfd0;   // v_pk_mul_f16
            h16x8 uu = pus0 + pud0;   // v_pk_add_f16
            int ph = (sc ^ (sed & 7)) << 3;
            *(h16x8*)(sP + sed * 128 + ph) = pp;
            *(h16x8*)(sU + sed * 128 + ph) = uu;
        }
        {
            int ed = sed + 32;
            h16x8 pp = pfs1 * pfd1;
            h16x8 uu = pus1 + pud1;
            int ph = (sc ^ (ed & 7)) << 3;
            *(h16x8*)(sP + ed * 128 + ph) = pp;
            *(h16x8*)(sU + ed * 128 + ph) = uu;
        }
        __syncthreads();  // stage visible (also fences prev iter's partials reads)
        // software pipeline: issue next tile's gathers now
        if (it + 1 < ES_ITERS) {
            int e1 = (blockIdx.x + (it + 1) * ES_NBLK) * 64;
            pk0 = csr[e1 + sed];
            pk1 = csr[e1 + sed + 32];
            pfs0 = *(const h16x8*)(fb + (size_t)pk0.x * DD + sc * 8);
            pfd0 = *(const h16x8*)(fb + (size_t)pk0.y * DD + sc * 8);
            pus0 = *(const h16x8*)(us + (size_t)pk0.x * DD + sc * 8);
            pud0 = *(const h16x8*)(ud + (size_t)pk0.y * DD + sc * 8);
            pfs1 = *(const h16x8*)(fb + (size_t)pk1.x * DD + sc * 8);
            pfd1 = *(const h16x8*)(fb + (size_t)pk1.y * DD + sc * 8);
            pus1 = *(const h16x8*)(us + (size_t)pk1.x * DD + sc * 8);
            pud1 = *(const h16x8*)(ud + (size_t)pk1.y * DD + sc * 8);
        }
        // one 32x32x128 matmul on this wave's edge group: acc[r] holds
        // ch = t*32 + (r&3)+8*(r>>2)+4q, edge = g*32 + n
        f32x16 acc = {};
        int row = g * 32 + n;
        int swz = n & 7;   // row & 7 == n & 7
#pragma unroll
        for (int kc = 0; kc < 8; kc++) {
            h16x8 bP = *(const h16x8*)(sP + row * 128 + (((kc * 2 + q) ^ swz) << 3));
            acc = __builtin_amdgcn_mfma_f32_32x32x16_f16(wAm[kc], bP, acc, 0, 0, 0);
        }
        float psum = 0.f;
#pragma unroll
        for (int c = 0; c < 4; c++) {
            h16x4 sv = *(const h16x4*)(sU + row * 128 + (((t * 4 + c) ^ swz) << 3) + q * 4);
            f32x4 wv = *(const f32x4*)(sWa + t * 32 + c * 8 + q * 4);
#pragma unroll
            for (int j = 0; j < 4; j++)
                psum = fmaf(gelu_f(acc[c * 4 + j] + (float)sv[j]), wv[j], psum);
        }
        psum += __shfl_xor(psum, 32, 64);
        if (lane < 32) partials[(g * 32 + lane) * 5 + t] = psum;
        __syncthreads();  // partials ready; all stage reads complete
        if (wave == (it & 7)) {
            const float* pr = partials + lane * 5;
            float s = pr[0] + pr[1] + pr[2] + pr[3] + bout;
            s = s > 0.f ? s : 0.2f * s;
            // sequential score store into the pre-permuted CSR slot (no atomics)
            csr[eb + lane].y = __float_as_int(s);
        }
    }
}

// ---------------- per-node aggregation over CSR (4 edges/iter) ----------------
__global__ __launch_bounds__(256) void aggregate_kernel(
    const h16_t* __restrict__ hh,
    const int* __restrict__ offsets, const int* __restrict__ deg,
    const int2* __restrict__ csr,
    h16_t* __restrict__ neigh, h16_t* __restrict__ neigh2)
{
    int wave = threadIdx.x >> 6, lane = threadIdx.x & 63;
    int v = blockIdx.x * 4 + wave;
    if (v >= NN) return;
    int off = offsets[v];
    int dg = deg[v];
    int quarter = lane >> 4;  // which edge of the quad
    int cl = lane & 15;       // 32B chunk id within the 512B row
    float mx[8], sm[8];
#pragma unroll
    for (int j = 0; j < 8; j++) { mx[j] = -INFINITY; sm[j] = 0.f; }
    for (int base = 0; base < dg; base += 64) {
        int cnt = dg - base; if (cnt > 64) cnt = 64;
        int s_l = 0; float sc_l = 0.f;
        if (lane < cnt) {
            int2 pk = csr[off + base + lane];
            s_l = pk.x;
            sc_l = __int_as_float(pk.y);
        }
        int nit = (cnt + 3) >> 2;
#pragma unroll 2
        for (int i = 0; i < nit; i++) {
            int idx = 4 * i + quarter;
            int s = __shfl(s_l, idx, 64);
            float sc = __shfl(sc_l, idx, 64);
            if (idx < cnt) {
                const h16_t* row = hh + (size_t)s * 256 + 16 * cl;
                h16x8 h0 = *(const h16x8*)(row);
                h16x8 h1 = *(const h16x8*)(row + 8);
                mx[0] = fmaxf(mx[0], sc * (float)h0[0]);
                mx[1] = fmaxf(mx[1], sc * (float)h0[1]);
                sm[0] = fmaf(sc, (float)h0[2], sm[0]);
                sm[1] = fmaf(sc, (float)h0[3], sm[1]);
                mx[2] = fmaxf(mx[2], sc * (float)h0[4]);
                mx[3] = fmaxf(mx[3], sc * (float)h0[5]);
                sm[2] = fmaf(sc, (float)h0[6], sm[2]);
                sm[3] = fmaf(sc, (float)h0[7], sm[3]);
                mx[4] = fmaxf(mx[4], sc * (float)h1[0]);
                mx[5] = fmaxf(mx[5], sc * (float)h1[1]);
                sm[4] = fmaf(sc, (float)h1[2], sm[4]);
                sm[5] = fmaf(sc, (float)h1[3], sm[5]);
                mx[6] = fmaxf(mx[6], sc * (float)h1[4]);
                mx[7] = fmaxf(mx[7], sc * (float)h1[5]);
                sm[6] = fmaf(sc, (float)h1[6], sm[6]);
                sm[7] = fmaf(sc, (float)h1[7], sm[7]);
            }
        }
    }
#pragma unroll
    for (int j = 0; j < 8; j++) {
        mx[j] = fmaxf(mx[j], __shfl_xor(mx[j], 16, 64));
        mx[j] = fmaxf(mx[j], __shfl_xor(mx[j], 32, 64));
        sm[j] += __shfl_xor(sm[j], 16, 64);
        sm[j] += __shfl_xor(sm[j], 32, 64);
    }
    if (quarter == 0) {
        float inv = 1.0f / (float)(dg > 1 ? dg : 1);
        h16x8 n1, n2;
#pragma unroll
        for (int j = 0; j < 8; j++) {
            n1[j] = (h16_t)(dg > 0 ? mx[j] : 0.0f);
            n2[j] = (h16_t)(sm[j] * inv);
        }
        *(h16x8*)(neigh + (size_t)v * DD + 8 * cl) = n1;
        *(h16x8*)(neigh2 + (size_t)v * DD + 8 * cl) = n2;
    }
}

// ---------------- final: self+neigh+neigh2 linears, then 2 MLP layers ----------------
__global__ __launch_bounds__(256) void final_kernel(
    const h16_t* __restrict__ fb, const h16_t* __restrict__ neigh, const h16_t* __restrict__ neigh2,
    const h16_t* __restrict__ W_selff, const h16_t* __restrict__ W_neighf, const h16_t* __restrict__ W_neigh2f,
    const float* __restrict__ b_rst,
    const h16_t* __restrict__ W_mlpf, const float* __restrict__ b_mlp,
    float* __restrict__ out)
{
    __shared__ __align__(16) float lds[4][16 * 132];
    int wave = threadIdx.x >> 6;
    int wid = blockIdx.x * 4 + wave;
    if (wid >= NN / 16) return;
    int lane = threadIdx.x & 63, n = lane & 15, q = lane >> 4;
    int nb = wid * 16;
    float* L = lds[wave];

    h16x8 af[4], an[4], am[4];
#pragma unroll
    for (int kb = 0; kb < 4; kb++) {
        size_t o = (size_t)(nb + n) * DD + kb * 32 + q * 8;
        af[kb] = *(const h16x8*)(fb + o);
        an[kb] = *(const h16x8*)(neigh + o);
        am[kb] = *(const h16x8*)(neigh2 + o);
    }
    f32x4 rst[8];
#pragma unroll
    for (int t = 0; t < 8; t++) {
        f32x4 acc = {0.f, 0.f, 0.f, 0.f};
#pragma unroll
        for (int kb = 0; kb < 4; kb++) {
            int wo = ((t * 4 + kb) * 64 + lane) << 3;
            acc = __builtin_amdgcn_mfma_f32_16x16x32_f16(af[kb], *(const h16x8*)(W_selff + wo), acc, 0, 0, 0);
            acc = __builtin_amdgcn_mfma_f32_16x16x32_f16(an[kb], *(const h16x8*)(W_neighf + wo), acc, 0, 0, 0);
            acc = __builtin_amdgcn_mfma_f32_16x16x32_f16(am[kb], *(const h16x8*)(W_neigh2f + wo), acc, 0, 0, 0);
        }
        float bv = b_rst[t * 16 + n];
#pragma unroll
        for (int r = 0; r < 4; r++) acc[r] += bv;
        rst[t] = acc;
    }

#pragma unroll
    for (int li = 0; li < 2; li++) {
#pragma unroll
        for (int t = 0; t < 8; t++)
#pragma unroll
            for (int r = 0; r < 4; r++)
                L[(q * 4 + r) * 132 + t * 16 + n] = gelu_f(rst[t][r]);
        __builtin_amdgcn_wave_barrier();
        h16x8 g[4];
#pragma unroll
        for (int kb = 0; kb < 4; kb++) {
            const f32x4* p = (const f32x4*)&L[n * 132 + kb * 32 + q * 8];
            f32x4 x0 = p[0], x1 = p[1];
            h16x8 gg;
            gg[0] = (h16_t)x0[0]; gg[1] = (h16_t)x0[1]; gg[2] = (h16_t)x0[2]; gg[3] = (h16_t)x0[3];
            gg[4] = (h16_t)x1[0]; gg[5] = (h16_t)x1[1]; gg[6] = (h16_t)x1[2]; gg[7] = (h16_t)x1[3];
            g[kb] = gg;
        }
        __builtin_amdgcn_wave_barrier();
        const h16_t* Wl = W_mlpf + li * DD * DD;
#pragma unroll
        for (int t = 0; t < 8; t++) {
            f32x4 acc = {0.f, 0.f, 0.f, 0.f};
#pragma unroll
            for (int kb = 0; kb < 4; kb++) {
                h16x8 b = *(const h16x8*)(Wl + (((t * 4 + kb) * 64 + lane) << 3));
                acc = __builtin_amdgcn_mfma_f32_16x16x32_f16(g[kb], b, acc, 0, 0, 0);
            }
            float bm = b_mlp[li * DD + t * 16 + n];
#pragma unroll
            for (int r = 0; r < 4; r++) rst[t][r] += acc[r] + bm;
        }
    }

#pragma unroll
    for (int t = 0; t < 8; t++)
#pragma unroll
        for (int r = 0; r < 4; r++)
            out[(size_t)(nb + q * 4 + r) * DD + t * 16 + n] = rst[t][r];
}

// ---------------- host launch ----------------
extern "C" void kernel_launch(void* const* d_in, const int* in_sizes, int n_in,
                              void* d_out, int out_size, void* d_ws, size_t ws_size,
                              hipStream_t stream)
{
    const float* feat    = (const float*)d_in[0];
    const int*   src     = (const int*)d_in[1];
    const int*   dst     = (const int*)d_in[2];
    const float* W_asrc  = (const float*)d_in[3],  *b_asrc  = (const float*)d_in[4];
    const float* W_adst  = (const float*)d_in[5],  *b_adst  = (const float*)d_in[6];
    const float* W_asub  = (const float*)d_in[7],  *b_asub  = (const float*)d_in[8];
    const float* W_amul  = (const float*)d_in[9],  *b_amul  = (const float*)d_in[10];
    const float* W_aout  = (const float*)d_in[11], *b_aout  = (const float*)d_in[12];
    const float* W_pool  = (const float*)d_in[13], *b_pool  = (const float*)d_in[14];
    const float* W_pool2 = (const float*)d_in[15], *b_pool2 = (const float*)d_in[16];
    const float* W_self  = (const float*)d_in[17], *b_self  = (const float*)d_in[18];
    const float* W_neigh = (const float*)d_in[19], *b_neigh = (const float*)d_in[20];
    const float* W_neigh2= (const float*)d_in[21], *b_neigh2= (const float*)d_in[22];
    const float* W_mlp   = (const float*)d_in[23], *b_mlp   = (const float*)d_in[24];
    float* out = (float*)d_out;

    char* w = (char*)d_ws;
    auto take = [&](size_t bytes) -> void* {
        void* p = (void*)w;
        w += (bytes + 255) & ~(size_t)255;
        return p;
    };
    h16_t* fb      = (h16_t*)take((size_t)NN * DD * sizeof(h16_t));
    h16_t* neigh   = (h16_t*)take((size_t)NN * DD * sizeof(h16_t));
    h16_t* neigh2  = (h16_t*)take((size_t)NN * DD * sizeof(h16_t));
    h16_t* hh      = (h16_t*)take((size_t)NN * 256 * sizeof(h16_t)); // h/h2 interleaved
    h16_t* us      = (h16_t*)take((size_t)NN * DD * sizeof(h16_t)); // (W_asrc+W_asub)·f + b_e
    h16_t* ud      = (h16_t*)take((size_t)NN * DD * sizeof(h16_t)); // (W_adst-W_asub)·f
    int*    deg     = (int*)take((size_t)NN * sizeof(int));
    int*    offsets = (int*)take((size_t)NN * sizeof(int));
    int2*   csr     = (int2*)take((size_t)NE * sizeof(int2));
    int2*   ebuf    = (int2*)take((size_t)NBK * BSLOT * sizeof(int2)); // slack bucket regions
    int*    gcursor = (int*)take((size_t)NBK * sizeof(int));
    h16_t* W_Sf    = (h16_t*)take((size_t)DD * DD * sizeof(h16_t));
    h16_t* W_Df    = (h16_t*)take((size_t)DD * DD * sizeof(h16_t));
    h16_t* W_amulf = (h16_t*)take((size_t)DD * DD * sizeof(h16_t));
    h16_t* W_poolf = (h16_t*)take((size_t)DD * DD * sizeof(h16_t));
    h16_t* W_pool2f= (h16_t*)take((size_t)DD * DD * sizeof(h16_t));
    h16_t* W_selff = (h16_t*)take((size_t)DD * DD * sizeof(h16_t));
    h16_t* W_neighf= (h16_t*)take((size_t)DD * DD * sizeof(h16_t));
    h16_t* W_neigh2f=(h16_t*)take((size_t)DD * DD * sizeof(h16_t));
    h16_t* W_mlpf  = (h16_t*)take((size_t)2 * DD * DD * sizeof(h16_t));
    float*  b_e     = (float*)take((size_t)DD * sizeof(float));
    float*  b_rst   = (float*)take((size_t)DD * sizeof(float));

    (void)hipMemsetAsync(gcursor, 0, (size_t)NBK * sizeof(int), stream);

    convert_feat_kernel<<<NN * DD / 4 / 256, 256, 0, stream>>>(feat, fb);

    prep_kernel<<<DD * DD / 256, 256, 0, stream>>>(
        W_asrc, b_asrc, W_adst, b_adst, W_asub, b_asub, W_amul, b_amul,
        W_pool, W_pool2, W_self, b_self, W_neigh, b_neigh, W_neigh2, b_neigh2, W_mlp,
        W_Sf, W_Df, W_amulf, W_poolf, W_pool2f, W_selff, W_neighf, W_neigh2f, W_mlpf,
        b_e, b_rst);

    // bucket-sort reorder: LDS-privatized histogram, 77k global atomics total
    scatter_bucket_kernel<<<(NE / 4 + 1023) / 1024, 256, 0, stream>>>(src, dst, gcursor, ebuf);
    finalize_csr_kernel<<<NBK, 256, 0, stream>>>(ebuf, gcursor, csr, offsets, deg);

    const int nwaves = NN / 16;                 // 3125
    const int ngrid = (nwaves + 3) / 4;         // 782
    node_linear_kernel<<<ngrid, 256, 0, stream>>>(
        fb, W_poolf, b_pool, W_pool2f, b_pool2, W_Sf, b_e, W_Df, hh, us, ud);

    edge_score_kernel<<<ES_NBLK, 512, 0, stream>>>(
        fb, us, ud, W_amulf, W_aout, b_aout, csr);

    aggregate_kernel<<<(NN + 3) / 4, 256, 0, stream>>>(
        hh, offsets, deg, csr, neigh, neigh2);

    final_kernel<<<ngrid, 256, 0, stream>>>(
        fb, neigh, neigh2, W_selff, W_neighf, W_neigh2f, b_rst, W_mlpf, b_mlp, out);
}

// Round 13
// 342.672 us; speedup vs baseline: 1.3953x; 1.3953x over previous
//
#include <hip/hip_runtime.h>
#include <cstdint>
#include <cstddef>

#define NN 50000
#define NE 800000
#define DD 128

#define NBK 391      // buckets of 128 nodes: (NN+127)>>7
#define BSLOT 4096   // slack slots per bucket (avg 2046, sd ~45 -> 45 sigma headroom)

static_assert(NN % 16 == 0, "node tiles");
static_assert(NE % 16 == 0, "edge tiles");
static_assert(((NN + 127) >> 7) == NBK, "bucket count");

typedef _Float16 h16_t;
typedef h16_t h16x8 __attribute__((ext_vector_type(8)));
typedef h16_t h16x4 __attribute__((ext_vector_type(4)));
typedef float f32x4 __attribute__((ext_vector_type(4)));
typedef float f32x16 __attribute__((ext_vector_type(16)));

// fast gelu: x * sigmoid(2*0.79788456*(x+0.044715x^3)) via v_exp_f32 + rcp (~1e-3 abs err)
__device__ __forceinline__ float gelu_f(float x) {
    float u = x * x;
    float t = fmaf(u, -0.1029442445f, -2.3021184019f);  // -(2log2e)*0.79788456*(1+0.044715u)
    float s = __builtin_amdgcn_exp2f(x * t);
    return x * __builtin_amdgcn_rcpf(1.0f + s);
}

// fragment-major weight index for 16x16x32 MFMA: element (ch,k) -> ((t*4+kb)*4+q)*16+n)*8+j
__device__ __forceinline__ int frag_idx(int ch, int k) {
    int t = ch >> 4, n = ch & 15;
    int kb = k >> 5, r = k & 31, q = r >> 3, j = r & 7;
    return ((((t * 4 + kb) * 4 + q) * 16 + n) << 3) + j;
}

// fragment-major weight index for 32x32x16 MFMA: lane(m=l&31,q=l>>5) holds W[t*32+m][kc*16+q*8+j]
__device__ __forceinline__ int frag32_idx(int ch, int k) {
    int t = ch >> 5, m = ch & 31;
    int kc = k >> 4, q = (k >> 3) & 1, j = k & 7;
    return ((((t * 8 + kc) * 2 + q) * 32 + m) << 3) + j;
}

// ---------------- feat f32 -> fp16 ----------------
__global__ __launch_bounds__(256) void convert_feat_kernel(
    const float* __restrict__ feat, h16_t* __restrict__ fb)
{
    int i = blockIdx.x * 256 + threadIdx.x;  // quad index; NN*DD/4 = 1.6M exact
    f32x4 v = ((const f32x4*)feat)[i];
    h16x4 o;
    o[0] = (h16_t)v[0]; o[1] = (h16_t)v[1]; o[2] = (h16_t)v[2]; o[3] = (h16_t)v[3];
    ((h16x4*)fb)[i] = o;
}

// ---------------- prep: combine + convert weights, combine biases ----------------
// W_Sf = asrc+asub, W_Df = adst-asub (16x16 frag-major, node kernel -> us/ud).
// W_amulf: 32x32 frag-major (edge kernel). All fp16.
__global__ __launch_bounds__(256) void prep_kernel(
    const float* __restrict__ W_asrc, const float* __restrict__ b_asrc,
    const float* __restrict__ W_adst, const float* __restrict__ b_adst,
    const float* __restrict__ W_asub, const float* __restrict__ b_asub,
    const float* __restrict__ W_amul, const float* __restrict__ b_amul,
    const float* __restrict__ W_pool, const float* __restrict__ W_pool2,
    const float* __restrict__ W_self, const float* __restrict__ b_self,
    const float* __restrict__ W_neigh, const float* __restrict__ b_neigh,
    const float* __restrict__ W_neigh2, const float* __restrict__ b_neigh2,
    const float* __restrict__ W_mlp,
    h16_t* __restrict__ W_Sf, h16_t* __restrict__ W_Df, h16_t* __restrict__ W_amulf,
    h16_t* __restrict__ W_poolf, h16_t* __restrict__ W_pool2f,
    h16_t* __restrict__ W_selff, h16_t* __restrict__ W_neighf, h16_t* __restrict__ W_neigh2f,
    h16_t* __restrict__ W_mlpf,
    float* __restrict__ b_e, float* __restrict__ b_rst)
{
    int gid = blockIdx.x * 256 + threadIdx.x;  // 64 blocks * 256 = 16384 = DD*DD
    float sub = W_asub[gid];
    int ch = gid >> 7, k = gid & 127;
    int fi = frag_idx(ch, k);
    W_Sf[fi] = (h16_t)(W_asrc[gid] + sub);
    W_Df[fi] = (h16_t)(W_adst[gid] - sub);
    W_amulf[frag32_idx(ch, k)] = (h16_t)W_amul[gid];
    W_poolf[fi]   = (h16_t)W_pool[gid];
    W_pool2f[fi]  = (h16_t)W_pool2[gid];
    W_selff[fi]   = (h16_t)W_self[gid];
    W_neighf[fi]  = (h16_t)W_neigh[gid];
    W_neigh2f[fi] = (h16_t)W_neigh2[gid];
    W_mlpf[fi]            = (h16_t)W_mlp[gid];
    W_mlpf[DD * DD + fi]  = (h16_t)W_mlp[DD * DD + gid];
    if (gid < DD) {
        b_e[gid]   = b_asub[gid] + b_amul[gid] + b_asrc[gid] + b_adst[gid];
        b_rst[gid] = b_self[gid] + b_neigh[gid] + b_neigh2[gid];
    }
}

// ---------------- bucket sort pass 1: LDS-privatized histogram + chunked scatter ----------------
__global__ __launch_bounds__(256) void scatter_bucket_kernel(
    const int* __restrict__ src, const int* __restrict__ dst,
    int* __restrict__ gcursor, int2* __restrict__ ebuf)
{
    __shared__ int cnt[NBK];
    __shared__ int ofs[NBK];
    int t = threadIdx.x;
    for (int b = t; b < NBK; b += 256) cnt[b] = 0;
    __syncthreads();
    int qbase = blockIdx.x * 1024 + t;
    int4 s4[4], d4[4];
    bool valid[4];
#pragma unroll
    for (int k = 0; k < 4; k++) {
        int q = qbase + k * 256;
        valid[k] = q < NE / 4;
        if (valid[k]) {
            s4[k] = ((const int4*)src)[q];
            d4[k] = ((const int4*)dst)[q];
#pragma unroll
            for (int j = 0; j < 4; j++)
                atomicAdd(&cnt[((&d4[k].x)[j]) >> 7], 1);
        }
    }
    __syncthreads();
    for (int b = t; b < NBK; b += 256) {
        int c = cnt[b];
        ofs[b] = c ? atomicAdd(&gcursor[b], c) : 0;
    }
    __syncthreads();
#pragma unroll
    for (int k = 0; k < 4; k++) {
        if (valid[k]) {
#pragma unroll
            for (int j = 0; j < 4; j++) {
                int d = (&d4[k].x)[j];
                int b = d >> 7;
                int p = atomicAdd(&ofs[b], 1);
                int2 pk;
                pk.x = (&s4[k].x)[j];
                pk.y = d;
                ebuf[(size_t)b * BSLOT + p] = pk;
            }
        }
    }
}

// ---------------- bucket sort pass 2: exact CSR within each bucket (fused prefix) ----------------
// dbase = sum(gcursor[0..B)) computed per-block via LDS reduce (391 ints, trivial).
__global__ __launch_bounds__(256) void finalize_csr_kernel(
    const int2* __restrict__ ebuf, const int* __restrict__ gcursor,
    int2* __restrict__ csr, int* __restrict__ offsets, int* __restrict__ deg)
{
    __shared__ int lcnt[128];
    __shared__ int nbase[128];
    __shared__ int pre[128];
    __shared__ int redbuf[256];
    int B = blockIdx.x, t = threadIdx.x;
    int v0 = B << 7;
    int cnt = gcursor[B];
    // block-local exclusive prefix over bucket counts
    int partial = 0;
    for (int i = t; i < B; i += 256) partial += gcursor[i];
    redbuf[t] = partial;
    __syncthreads();
#pragma unroll
    for (int d = 128; d > 0; d >>= 1) {
        if (t < d) redbuf[t] += redbuf[t + d];
        __syncthreads();
    }
    int dbase = redbuf[0];
    const int2* eb = ebuf + (size_t)B * BSLOT;
    if (t < 128) lcnt[t] = 0;
    __syncthreads();
    for (int i = t; i < cnt; i += 256)
        atomicAdd(&lcnt[eb[i].y - v0], 1);
    __syncthreads();
    int c = (t < 128) ? lcnt[t] : 0;
    if (t < 128) pre[t] = c;
    __syncthreads();
#pragma unroll
    for (int d = 1; d < 128; d <<= 1) {
        int x = (t >= d && t < 128) ? pre[t - d] : 0;
        __syncthreads();
        if (t < 128) pre[t] += x;
        __syncthreads();
    }
    if (t < 128) {
        int nb = dbase + pre[t] - c;  // exclusive prefix -> node base in dense csr
        nbase[t] = nb;
        int v = v0 + t;
        if (v < NN) { offsets[v] = nb; deg[v] = c; }
        lcnt[t] = 0;
    }
    __syncthreads();
    for (int i = t; i < cnt; i += 256) {
        int2 pk = eb[i];
        int j = pk.y - v0;
        int pos = nbase[j] + atomicAdd(&lcnt[j], 1);
        csr[pos] = pk;
    }
}

// ---------------- node_linear: MFMA -> LDS transpose -> wide coalesced stores ----------------
template <bool GELU>
__device__ __forceinline__ void mm16_to_lds(
    const h16x8 a[4], const h16_t* __restrict__ Wf, const float* __restrict__ bias,
    h16_t* __restrict__ L, int n, int q, int lane)
{
#pragma unroll
    for (int t = 0; t < 8; t++) {
        f32x4 acc = {0.f, 0.f, 0.f, 0.f};
#pragma unroll
        for (int kb = 0; kb < 4; kb++) {
            h16x8 b = *(const h16x8*)(Wf + (((t * 4 + kb) * 64 + lane) << 3));
            acc = __builtin_amdgcn_mfma_f32_16x16x32_f16(a[kb], b, acc, 0, 0, 0);
        }
        int ch = t * 16 + n;
        float bv = bias ? bias[ch] : 0.0f;
#pragma unroll
        for (int r = 0; r < 4; r++) {
            float v = acc[r] + bv;
            L[(q * 4 + r) * 136 + ch] = (h16_t)(GELU ? gelu_f(v) : v);
        }
    }
}

__global__ __launch_bounds__(256) void node_linear_kernel(
    const h16_t* __restrict__ fb,
    const h16_t* __restrict__ W_poolf, const float* __restrict__ b_pool,
    const h16_t* __restrict__ W_pool2f, const float* __restrict__ b_pool2,
    const h16_t* __restrict__ W_Sf, const float* __restrict__ b_e,
    const h16_t* __restrict__ W_Df,
    h16_t* __restrict__ hh, h16_t* __restrict__ us, h16_t* __restrict__ ud)
{
    __shared__ __align__(16) h16_t Lh[4][16 * 136];
    __shared__ __align__(16) h16_t Lh2[4][16 * 136];
    int wave = threadIdx.x >> 6;
    int wid = blockIdx.x * 4 + wave;
    if (wid >= NN / 16) return;
    int lane = threadIdx.x & 63, n = lane & 15, q = lane >> 4;
    int nb = wid * 16;
    h16_t* lh = Lh[wave];
    h16_t* lh2 = Lh2[wave];
    h16x8 a[4];
#pragma unroll
    for (int kb = 0; kb < 4; kb++)
        a[kb] = *(const h16x8*)(fb + (size_t)(nb + n) * DD + kb * 32 + q * 8);

    // h -> lh, h2 -> lh2 (gelu'd fp16)
    mm16_to_lds<true>(a, W_poolf, b_pool, lh, n, q, lane);
    mm16_to_lds<true>(a, W_pool2f, b_pool2, lh2, n, q, lane);
    __builtin_amdgcn_wave_barrier();
    // interleaved hh store: chunk c (16B) = {h[4c],h[4c+1],h2[4c],h2[4c+1],h[4c+2],h[4c+3],h2[4c+2],h2[4c+3]}
#pragma unroll
    for (int i = 0; i < 8; i++) {
        int r = 2 * i + (lane >> 5);
        int c = lane & 31;
        h16x4 xh = *(const h16x4*)(lh + r * 136 + 4 * c);
        h16x4 x2 = *(const h16x4*)(lh2 + r * 136 + 4 * c);
        h16x8 o;
        o[0] = xh[0]; o[1] = xh[1]; o[2] = x2[0]; o[3] = x2[1];
        o[4] = xh[2]; o[5] = xh[3]; o[6] = x2[2]; o[7] = x2[3];
        *(h16x8*)(hh + (size_t)(nb + r) * 256 + 8 * c) = o;
    }
    __builtin_amdgcn_wave_barrier();
    // us = (W_asrc+W_asub)·f + b_e
    mm16_to_lds<false>(a, W_Sf, b_e, lh, n, q, lane);
    __builtin_amdgcn_wave_barrier();
#pragma unroll
    for (int i = 0; i < 4; i++) {
        int r = 4 * i + (lane >> 4);
        int c = lane & 15;
        *(h16x8*)(us + (size_t)(nb + r) * 128 + 8 * c) = *(const h16x8*)(lh + r * 136 + 8 * c);
    }
    __builtin_amdgcn_wave_barrier();
    // ud = (W_adst-W_asub)·f
    mm16_to_lds<false>(a, W_Df, nullptr, lh, n, q, lane);
    __builtin_amdgcn_wave_barrier();
#pragma unroll
    for (int i = 0; i < 4; i++) {
        int r = 4 * i + (lane >> 4);
        int c = lane & 15;
        *(h16x8*)(ud + (size_t)(nb + r) * 128 + 8 * c) = *(const h16x8*)(lh + r * 136 + 8 * c);
    }
}

// ---------------- per-edge score over dst-sorted list (R11 form: 256thr, fp16, 1-buf) ----------------
// e_ch = gelu( W_amul·(fs∘fd) + us[src] + ud[dst] ). Edges in CSR(dst) order.
// fp16 packed staging (v_pk_mul/add_f16); single-buffer LDS (17.5KB); 60 VGPR (measured
// 71.8us). R12 lesson: do NOT raise min-waves bound — the prefetch pipeline needs ~64
// live VGPRs; launch_bounds(512,8) forced 32 VGPR and spilled everything to scratch.
#define ES_NBLK 2500
#define ES_ITERS (NE / 32 / ES_NBLK)   // 10

__global__ __launch_bounds__(256, 4) void edge_score_kernel(
    const h16_t* __restrict__ fb,
    const h16_t* __restrict__ us, const h16_t* __restrict__ ud,
    const h16_t* __restrict__ W_amulf,
    const float* __restrict__ w_aout, const float* __restrict__ b_aout,
    int2* __restrict__ csr)
{
    __shared__ __align__(16) h16_t sP[32 * 128];
    __shared__ __align__(16) h16_t sU[32 * 128];
    __shared__ float partials[32 * 5];   // [edge][wave], stride 5 to kill bank conflicts
    __shared__ float sWa[128];
    int tid = threadIdx.x;
    int wave = tid >> 6, lane = tid & 63;
    int n = lane & 31, q = lane >> 5;
    int t = wave;  // channel tile (32 ch)

    if (tid < 128) sWa[tid] = w_aout[tid];

    // persistent weight A-frags: lane(m=n,q) holds W[t*32+n][kc*16+q*8 .. +7]
    h16x8 wAm[8];
#pragma unroll
    for (int kc = 0; kc < 8; kc++)
        wAm[kc] = *(const h16x8*)(W_amulf + ((((t * 8 + kc) * 2 + q) * 32 + n) << 3));
    float bout = b_aout[0];

    // staging role: thread -> edges sed0, sed0+16; 16B chunk sc (0..15)
    int sed0 = tid >> 4, sc = tid & 15;

    // prefetch tile 0 ({src,dst} read sequentially from csr)
    int e0 = blockIdx.x * 32;
    int2 pk0 = csr[e0 + sed0];
    int2 pk1 = csr[e0 + sed0 + 16];
    h16x8 pfs0 = *(const h16x8*)(fb + (size_t)pk0.x * DD + sc * 8);
    h16x8 pfd0 = *(const h16x8*)(fb + (size_t)pk0.y * DD + sc * 8);
    h16x8 pus0 = *(const h16x8*)(us + (size_t)pk0.x * DD + sc * 8);
    h16x8 pud0 = *(const h16x8*)(ud + (size_t)pk0.y * DD + sc * 8);
    h16x8 pfs1 = *(const h16x8*)(fb + (size_t)pk1.x * DD + sc * 8);
    h16x8 pfd1 = *(const h16x8*)(fb + (size_t)pk1.y * DD + sc * 8);
    h16x8 pus1 = *(const h16x8*)(us + (size_t)pk1.x * DD + sc * 8);
    h16x8 pud1 = *(const h16x8*)(ud + (size_t)pk1.y * DD + sc * 8);

    for (int it = 0; it < ES_ITERS; it++) {
        int eb = (blockIdx.x + it * ES_NBLK) * 32;
        {
            h16x8 pp = pfs0 * pfd0;   // v_pk_mul_f16
            h16x8 uu = pus0 + pud0;   // v_pk_add_f16
            int ph = (sc ^ (sed0 & 7)) << 3;
            *(h16x8*)(sP + sed0 * 128 + ph) = pp;
            *(h16x8*)(sU + sed0 * 128 + ph) = uu;
        }
        {
            int ed = sed0 + 16;
            h16x8 pp = pfs1 * pfd1;
            h16x8 uu = pus1 + pud1;
            int ph = (sc ^ (ed & 7)) << 3;
            *(h16x8*)(sP + ed * 128 + ph) = pp;
            *(h16x8*)(sU + ed * 128 + ph) = uu;
        }
        __syncthreads();  // stage visible (also fences prev iter's partials reads)
        // software pipeline: issue next tile's gathers now
        if (it + 1 < ES_ITERS) {
            int e1 = (blockIdx.x + (it + 1) * ES_NBLK) * 32;
            pk0 = csr[e1 + sed0];
            pk1 = csr[e1 + sed0 + 16];
            pfs0 = *(const h16x8*)(fb + (size_t)pk0.x * DD + sc * 8);
            pfd0 = *(const h16x8*)(fb + (size_t)pk0.y * DD + sc * 8);
            pus0 = *(const h16x8*)(us + (size_t)pk0.x * DD + sc * 8);
            pud0 = *(const h16x8*)(ud + (size_t)pk0.y * DD + sc * 8);
            pfs1 = *(const h16x8*)(fb + (size_t)pk1.x * DD + sc * 8);
            pfd1 = *(const h16x8*)(fb + (size_t)pk1.y * DD + sc * 8);
            pus1 = *(const h16x8*)(us + (size_t)pk1.x * DD + sc * 8);
            pud1 = *(const h16x8*)(ud + (size_t)pk1.y * DD + sc * 8);
        }
        // one 32x32x128 matmul: acc[r] holds ch = t*32 + (r&3)+8*(r>>2)+4q, edge = n
        f32x16 acc = {};
        int swz = n & 7;
#pragma unroll
        for (int kc = 0; kc < 8; kc++) {
            h16x8 bP = *(const h16x8*)(sP + n * 128 + (((kc * 2 + q) ^ swz) << 3));
            acc = __builtin_amdgcn_mfma_f32_32x32x16_f16(wAm[kc], bP, acc, 0, 0, 0);
        }
        float psum = 0.f;
#pragma unroll
        for (int c = 0; c < 4; c++) {
            h16x4 sv = *(const h16x4*)(sU + n * 128 + (((t * 4 + c) ^ swz) << 3) + q * 4);
            f32x4 wv = *(const f32x4*)(sWa + t * 32 + c * 8 + q * 4);
#pragma unroll
            for (int j = 0; j < 4; j++)
                psum = fmaf(gelu_f(acc[c * 4 + j] + (float)sv[j]), wv[j], psum);
        }
        psum += __shfl_xor(psum, 32, 64);
        if (lane < 32) partials[lane * 5 + wave] = psum;
        __syncthreads();  // partials ready; all stage reads complete
        if (wave == (it & 3) && lane < 32) {
            const float* pr = partials + lane * 5;
            float s = pr[0] + pr[1] + pr[2] + pr[3] + bout;
            s = s > 0.f ? s : 0.2f * s;
            // sequential score store into the pre-permuted CSR slot (no atomics)
            csr[eb + lane].y = __float_as_int(s);
        }
    }
}

// ---------------- per-node aggregation over CSR (4 edges/iter) ----------------
__global__ __launch_bounds__(256) void aggregate_kernel(
    const h16_t* __restrict__ hh,
    const int* __restrict__ offsets, const int* __restrict__ deg,
    const int2* __restrict__ csr,
    h16_t* __restrict__ neigh, h16_t* __restrict__ neigh2)
{
    int wave = threadIdx.x >> 6, lane = threadIdx.x & 63;
    int v = blockIdx.x * 4 + wave;
    if (v >= NN) return;
    int off = offsets[v];
    int dg = deg[v];
    int quarter = lane >> 4;  // which edge of the quad
    int cl = lane & 15;       // 32B chunk id within the 512B row
    float mx[8], sm[8];
#pragma unroll
    for (int j = 0; j < 8; j++) { mx[j] = -INFINITY; sm[j] = 0.f; }
    for (int base = 0; base < dg; base += 64) {
        int cnt = dg - base; if (cnt > 64) cnt = 64;
        int s_l = 0; float sc_l = 0.f;
        if (lane < cnt) {
            int2 pk = csr[off + base + lane];
            s_l = pk.x;
            sc_l = __int_as_float(pk.y);
        }
        int nit = (cnt + 3) >> 2;
#pragma unroll 2
        for (int i = 0; i < nit; i++) {
            int idx = 4 * i + quarter;
            int s = __shfl(s_l, idx, 64);
            float sc = __shfl(sc_l, idx, 64);
            if (idx < cnt) {
                const h16_t* row = hh + (size_t)s * 256 + 16 * cl;
                h16x8 h0 = *(const h16x8*)(row);
                h16x8 h1 = *(const h16x8*)(row + 8);
                mx[0] = fmaxf(mx[0], sc * (float)h0[0]);
                mx[1] = fmaxf(mx[1], sc * (float)h0[1]);
                sm[0] = fmaf(sc, (float)h0[2], sm[0]);
                sm[1] = fmaf(sc, (float)h0[3], sm[1]);
                mx[2] = fmaxf(mx[2], sc * (float)h0[4]);
                mx[3] = fmaxf(mx[3], sc * (float)h0[5]);
                sm[2] = fmaf(sc, (float)h0[6], sm[2]);
                sm[3] = fmaf(sc, (float)h0[7], sm[3]);
                mx[4] = fmaxf(mx[4], sc * (float)h1[0]);
                mx[5] = fmaxf(mx[5], sc * (float)h1[1]);
                sm[4] = fmaf(sc, (float)h1[2], sm[4]);
                sm[5] = fmaf(sc, (float)h1[3], sm[5]);
                mx[6] = fmaxf(mx[6], sc * (float)h1[4]);
                mx[7] = fmaxf(mx[7], sc * (float)h1[5]);
                sm[6] = fmaf(sc, (float)h1[6], sm[6]);
                sm[7] = fmaf(sc, (float)h1[7], sm[7]);
            }
        }
    }
#pragma unroll
    for (int j = 0; j < 8; j++) {
        mx[j] = fmaxf(mx[j], __shfl_xor(mx[j], 16, 64));
        mx[j] = fmaxf(mx[j], __shfl_xor(mx[j], 32, 64));
        sm[j] += __shfl_xor(sm[j], 16, 64);
        sm[j] += __shfl_xor(sm[j], 32, 64);
    }
    if (quarter == 0) {
        float inv = 1.0f / (float)(dg > 1 ? dg : 1);
        h16x8 n1, n2;
#pragma unroll
        for (int j = 0; j < 8; j++) {
            n1[j] = (h16_t)(dg > 0 ? mx[j] : 0.0f);
            n2[j] = (h16_t)(sm[j] * inv);
        }
        *(h16x8*)(neigh + (size_t)v * DD + 8 * cl) = n1;
        *(h16x8*)(neigh2 + (size_t)v * DD + 8 * cl) = n2;
    }
}

// ---------------- final: self+neigh+neigh2 linears, then 2 MLP layers ----------------
__global__ __launch_bounds__(256) void final_kernel(
    const h16_t* __restrict__ fb, const h16_t* __restrict__ neigh, const h16_t* __restrict__ neigh2,
    const h16_t* __restrict__ W_selff, const h16_t* __restrict__ W_neighf, const h16_t* __restrict__ W_neigh2f,
    const float* __restrict__ b_rst,
    const h16_t* __restrict__ W_mlpf, const float* __restrict__ b_mlp,
    float* __restrict__ out)
{
    __shared__ __align__(16) float lds[4][16 * 132];
    int wave = threadIdx.x >> 6;
    int wid = blockIdx.x * 4 + wave;
    if (wid >= NN / 16) return;
    int lane = threadIdx.x & 63, n = lane & 15, q = lane >> 4;
    int nb = wid * 16;
    float* L = lds[wave];

    h16x8 af[4], an[4], am[4];
#pragma unroll
    for (int kb = 0; kb < 4; kb++) {
        size_t o = (size_t)(nb + n) * DD + kb * 32 + q * 8;
        af[kb] = *(const h16x8*)(fb + o);
        an[kb] = *(const h16x8*)(neigh + o);
        am[kb] = *(const h16x8*)(neigh2 + o);
    }
    f32x4 rst[8];
#pragma unroll
    for (int t = 0; t < 8; t++) {
        f32x4 acc = {0.f, 0.f, 0.f, 0.f};
#pragma unroll
        for (int kb = 0; kb < 4; kb++) {
            int wo = ((t * 4 + kb) * 64 + lane) << 3;
            acc = __builtin_amdgcn_mfma_f32_16x16x32_f16(af[kb], *(const h16x8*)(W_selff + wo), acc, 0, 0, 0);
            acc = __builtin_amdgcn_mfma_f32_16x16x32_f16(an[kb], *(const h16x8*)(W_neighf + wo), acc, 0, 0, 0);
            acc = __builtin_amdgcn_mfma_f32_16x16x32_f16(am[kb], *(const h16x8*)(W_neigh2f + wo), acc, 0, 0, 0);
        }
        float bv = b_rst[t * 16 + n];
#pragma unroll
        for (int r = 0; r < 4; r++) acc[r] += bv;
        rst[t] = acc;
    }

#pragma unroll
    for (int li = 0; li < 2; li++) {
#pragma unroll
        for (int t = 0; t < 8; t++)
#pragma unroll
            for (int r = 0; r < 4; r++)
                L[(q * 4 + r) * 132 + t * 16 + n] = gelu_f(rst[t][r]);
        __builtin_amdgcn_wave_barrier();
        h16x8 g[4];
#pragma unroll
        for (int kb = 0; kb < 4; kb++) {
            const f32x4* p = (const f32x4*)&L[n * 132 + kb * 32 + q * 8];
            f32x4 x0 = p[0], x1 = p[1];
            h16x8 gg;
            gg[0] = (h16_t)x0[0]; gg[1] = (h16_t)x0[1]; gg[2] = (h16_t)x0[2]; gg[3] = (h16_t)x0[3];
            gg[4] = (h16_t)x1[0]; gg[5] = (h16_t)x1[1]; gg[6] = (h16_t)x1[2]; gg[7] = (h16_t)x1[3];
            g[kb] = gg;
        }
        __builtin_amdgcn_wave_barrier();
        const h16_t* Wl = W_mlpf + li * DD * DD;
#pragma unroll
        for (int t = 0; t < 8; t++) {
            f32x4 acc = {0.f, 0.f, 0.f, 0.f};
#pragma unroll
            for (int kb = 0; kb < 4; kb++) {
                h16x8 b = *(const h16x8*)(Wl + (((t * 4 + kb) * 64 + lane) << 3));
                acc = __builtin_amdgcn_mfma_f32_16x16x32_f16(g[kb], b, acc, 0, 0, 0);
            }
            float bm = b_mlp[li * DD + t * 16 + n];
#pragma unroll
            for (int r = 0; r < 4; r++) rst[t][r] += acc[r] + bm;
        }
    }

#pragma unroll
    for (int t = 0; t < 8; t++)
#pragma unroll
        for (int r = 0; r < 4; r++)
            out[(size_t)(nb + q * 4 + r) * DD + t * 16 + n] = rst[t][r];
}

// ---------------- host launch ----------------
extern "C" void kernel_launch(void* const* d_in, const int* in_sizes, int n_in,
                              void* d_out, int out_size, void* d_ws, size_t ws_size,
                              hipStream_t stream)
{
    const float* feat    = (const float*)d_in[0];
    const int*   src     = (const int*)d_in[1];
    const int*   dst     = (const int*)d_in[2];
    const float* W_asrc  = (const float*)d_in[3],  *b_asrc  = (const float*)d_in[4];
    const float* W_adst  = (const float*)d_in[5],  *b_adst  = (const float*)d_in[6];
    const float* W_asub  = (const float*)d_in[7],  *b_asub  = (const float*)d_in[8];
    const float* W_amul  = (const float*)d_in[9],  *b_amul  = (const float*)d_in[10];
    const float* W_aout  = (const float*)d_in[11], *b_aout  = (const float*)d_in[12];
    const float* W_pool  = (const float*)d_in[13], *b_pool  = (const float*)d_in[14];
    const float* W_pool2 = (const float*)d_in[15], *b_pool2 = (const float*)d_in[16];
    const float* W_self  = (const float*)d_in[17], *b_self  = (const float*)d_in[18];
    const float* W_neigh = (const float*)d_in[19], *b_neigh = (const float*)d_in[20];
    const float* W_neigh2= (const float*)d_in[21], *b_neigh2= (const float*)d_in[22];
    const float* W_mlp   = (const float*)d_in[23], *b_mlp   = (const float*)d_in[24];
    float* out = (float*)d_out;

    char* w = (char*)d_ws;
    auto take = [&](size_t bytes) -> void* {
        void* p = (void*)w;
        w += (bytes + 255) & ~(size_t)255;
        return p;
    };
    h16_t* fb      = (h16_t*)take((size_t)NN * DD * sizeof(h16_t));
    h16_t* neigh   = (h16_t*)take((size_t)NN * DD * sizeof(h16_t));
    h16_t* neigh2  = (h16_t*)take((size_t)NN * DD * sizeof(h16_t));
    h16_t* hh      = (h16_t*)take((size_t)NN * 256 * sizeof(h16_t)); // h/h2 interleaved
    h16_t* us      = (h16_t*)take((size_t)NN * DD * sizeof(h16_t)); // (W_asrc+W_asub)·f + b_e
    h16_t* ud      = (h16_t*)take((size_t)NN * DD * sizeof(h16_t)); // (W_adst-W_asub)·f
    int*    deg     = (int*)take((size_t)NN * sizeof(int));
    int*    offsets = (int*)take((size_t)NN * sizeof(int));
    int2*   csr     = (int2*)take((size_t)NE * sizeof(int2));
    int2*   ebuf    = (int2*)take((size_t)NBK * BSLOT * sizeof(int2)); // slack bucket regions
    int*    gcursor = (int*)take((size_t)NBK * sizeof(int));
    h16_t* W_Sf    = (h16_t*)take((size_t)DD * DD * sizeof(h16_t));
    h16_t* W_Df    = (h16_t*)take((size_t)DD * DD * sizeof(h16_t));
    h16_t* W_amulf = (h16_t*)take((size_t)DD * DD * sizeof(h16_t));
    h16_t* W_poolf = (h16_t*)take((size_t)DD * DD * sizeof(h16_t));
    h16_t* W_pool2f= (h16_t*)take((size_t)DD * DD * sizeof(h16_t));
    h16_t* W_selff = (h16_t*)take((size_t)DD * DD * sizeof(h16_t));
    h16_t* W_neighf= (h16_t*)take((size_t)DD * DD * sizeof(h16_t));
    h16_t* W_neigh2f=(h16_t*)take((size_t)DD * DD * sizeof(h16_t));
    h16_t* W_mlpf  = (h16_t*)take((size_t)2 * DD * DD * sizeof(h16_t));
    float*  b_e     = (float*)take((size_t)DD * sizeof(float));
    float*  b_rst   = (float*)take((size_t)DD * sizeof(float));

    (void)hipMemsetAsync(gcursor, 0, (size_t)NBK * sizeof(int), stream);

    convert_feat_kernel<<<NN * DD / 4 / 256, 256, 0, stream>>>(feat, fb);

    prep_kernel<<<DD * DD / 256, 256, 0, stream>>>(
        W_asrc, b_asrc, W_adst, b_adst, W_asub, b_asub, W_amul, b_amul,
        W_pool, W_pool2, W_self, b_self, W_neigh, b_neigh, W_neigh2, b_neigh2, W_mlp,
        W_Sf, W_Df, W_amulf, W_poolf, W_pool2f, W_selff, W_neighf, W_neigh2f, W_mlpf,
        b_e, b_rst);

    // bucket-sort reorder: LDS-privatized histogram, 77k global atomics total
    scatter_bucket_kernel<<<(NE / 4 + 1023) / 1024, 256, 0, stream>>>(src, dst, gcursor, ebuf);
    finalize_csr_kernel<<<NBK, 256, 0, stream>>>(ebuf, gcursor, csr, offsets, deg);

    const int nwaves = NN / 16;                 // 3125
    const int ngrid = (nwaves + 3) / 4;         // 782
    node_linear_kernel<<<ngrid, 256, 0, stream>>>(
        fb, W_poolf, b_pool, W_pool2f, b_pool2, W_Sf, b_e, W_Df, hh, us, ud);

    edge_score_kernel<<<ES_NBLK, 256, 0, stream>>>(
        fb, us, ud, W_amulf, W_aout, b_aout, csr);

    aggregate_kernel<<<(NN + 3) / 4, 256, 0, stream>>>(
        hh, offsets, deg, csr, neigh, neigh2);

    final_kernel<<<ngrid, 256, 0, stream>>>(
        fb, neigh, neigh2, W_selff, W_neighf, W_neigh2f, b_rst, W_mlpf, b_mlp, out);
}